// Round 1
// baseline (606.913 us; speedup 1.0000x reference)
//
#include <hip/hip_runtime.h>
#include <math.h>

#define D_MODEL 768
#define D_FFN   3072
#define RANK    16
#define SEQ     64
#define MOD_SCALE 0.1f

// Kernel 1: mod[s][r] = MOD_SCALE * tanh( sum_d attn[s][d] * A[d][r] )
// grid: 64 blocks (one per s), block: 256 threads (16 d-chunks x 16 r)
__global__ __launch_bounds__(256)
void mod_kernel(const float* __restrict__ attn,
                const float* __restrict__ A,
                float* __restrict__ mod) {
    const int s = blockIdx.x;
    const int t = threadIdx.x;
    const int r = t & 15;          // which rank column
    const int chunk = t >> 4;      // 0..15, each covers 48 d's
    const float* arow = attn + s * D_MODEL;

    float partial = 0.0f;
    const int d0 = chunk * (D_MODEL / 16);   // 48 d's per chunk
    #pragma unroll 4
    for (int i = 0; i < D_MODEL / 16; ++i) {
        const int d = d0 + i;
        partial += arow[d] * A[d * RANK + r];
    }

    __shared__ float part[256];
    part[chunk * 16 + r] = partial;
    __syncthreads();

    if (t < RANK) {
        float sum = 0.0f;
        #pragma unroll
        for (int c = 0; c < 16; ++c) sum += part[c * 16 + t];
        mod[s * RANK + t] = MOD_SCALE * tanhf(sum);
    }
}

// Kernel 2: delta_w[s][d][f] = sum_r A[d][r] * (mod[s][r] * B[r][f])
// grid: (D_FFN/1024, D_MODEL/16, SEQ)  block: 256 threads
// each thread owns one float4 f-column, iterates 16 d's with wave-uniform A.
__global__ __launch_bounds__(256)
void delta_kernel(const float* __restrict__ A,
                  const float* __restrict__ B,
                  const float* __restrict__ mod,
                  float* __restrict__ out) {
    const int tid    = threadIdx.x;
    const int s      = blockIdx.z;
    const int d_base = blockIdx.y * 16;
    const int f      = blockIdx.x * 1024 + tid * 4;

    // Load B fragment for this thread's f-column and pre-scale by mod[s][r].
    float4 Bs[RANK];
    #pragma unroll
    for (int r = 0; r < RANK; ++r) {
        const float4 b = *(const float4*)(B + r * D_FFN + f);
        const float  m = mod[s * RANK + r];   // wave-uniform -> scalar load
        Bs[r].x = m * b.x;
        Bs[r].y = m * b.y;
        Bs[r].z = m * b.z;
        Bs[r].w = m * b.w;
    }

    float* outp = out + ((size_t)(s * D_MODEL + d_base)) * D_FFN + f;

    #pragma unroll
    for (int dl = 0; dl < 16; ++dl) {
        const float* Ad = A + (size_t)(d_base + dl) * RANK;  // wave-uniform base
        float4 acc = make_float4(0.f, 0.f, 0.f, 0.f);
        #pragma unroll
        for (int r = 0; r < RANK; ++r) {
            const float a = Ad[r];            // wave-uniform -> s_load + SGPR-operand FMA
            acc.x = fmaf(a, Bs[r].x, acc.x);
            acc.y = fmaf(a, Bs[r].y, acc.y);
            acc.z = fmaf(a, Bs[r].z, acc.z);
            acc.w = fmaf(a, Bs[r].w, acc.w);
        }
        __builtin_nontemporal_store(acc.x, outp + 0);
        __builtin_nontemporal_store(acc.y, outp + 1);
        __builtin_nontemporal_store(acc.z, outp + 2);
        __builtin_nontemporal_store(acc.w, outp + 3);
        outp += D_FFN;
    }
}

extern "C" void kernel_launch(void* const* d_in, const int* in_sizes, int n_in,
                              void* d_out, int out_size, void* d_ws, size_t ws_size,
                              hipStream_t stream) {
    const float* attn = (const float*)d_in[0];   // (1, 64, 768)
    const float* A    = (const float*)d_in[1];   // (768, 16)
    const float* B    = (const float*)d_in[2];   // (16, 3072)
    float*       out  = (float*)d_out;           // (1, 64, 768, 3072)
    float*       mod  = (float*)d_ws;            // 64*16 floats scratch

    hipLaunchKernelGGL(mod_kernel, dim3(SEQ), dim3(256), 0, stream, attn, A, mod);
    hipLaunchKernelGGL(delta_kernel,
                       dim3(D_FFN / 1024, D_MODEL / 16, SEQ), dim3(256), 0, stream,
                       A, B, mod, out);
}

// Round 2
// 602.168 us; speedup vs baseline: 1.0079x; 1.0079x over previous
//
#include <hip/hip_runtime.h>
#include <math.h>

#define D_MODEL 768
#define D_FFN   3072
#define RANK    16
#define SEQ     64
#define MOD_SCALE 0.1f

typedef float v4f __attribute__((ext_vector_type(4)));

// Kernel 1: mod[s][r] = MOD_SCALE * tanh( sum_d attn[s][d] * A[d][r] )
// grid: 64 blocks (one per s), block: 256 threads (16 d-chunks x 16 r)
__global__ __launch_bounds__(256)
void mod_kernel(const float* __restrict__ attn,
                const float* __restrict__ A,
                float* __restrict__ mod) {
    const int s = blockIdx.x;
    const int t = threadIdx.x;
    const int r = t & 15;          // which rank column
    const int chunk = t >> 4;      // 0..15, each covers 48 d's
    const float* arow = attn + s * D_MODEL;

    float partial = 0.0f;
    const int d0 = chunk * (D_MODEL / 16);   // 48 d's per chunk
    #pragma unroll 4
    for (int i = 0; i < D_MODEL / 16; ++i) {
        const int d = d0 + i;
        partial += arow[d] * A[d * RANK + r];
    }

    __shared__ float part[256];
    part[chunk * 16 + r] = partial;
    __syncthreads();

    if (t < RANK) {
        float sum = 0.0f;
        #pragma unroll
        for (int c = 0; c < 16; ++c) sum += part[c * 16 + t];
        mod[s * RANK + t] = MOD_SCALE * tanhf(sum);
    }
}

// Kernel 2: delta_w[s][d][f] = sum_r A[d][r] * (mod[s][r] * B[r][f])
// grid: (D_FFN/1024, D_MODEL/16, SEQ)  block: 256 threads
// each thread owns one float4 f-column, iterates 16 d's with wave-uniform A.
// Store is ONE 16B nontemporal dwordx4 per d (full-line coverage per wave;
// the 4x scalar-nt-store version caused partial-line RMW -> 607us).
__global__ __launch_bounds__(256)
void delta_kernel(const float* __restrict__ A,
                  const float* __restrict__ B,
                  const float* __restrict__ mod,
                  float* __restrict__ out) {
    const int tid    = threadIdx.x;
    const int s      = blockIdx.z;
    const int d_base = blockIdx.y * 16;
    const int f      = blockIdx.x * 1024 + tid * 4;

    // Load B fragment for this thread's f-column and pre-scale by mod[s][r].
    v4f Bs[RANK];
    #pragma unroll
    for (int r = 0; r < RANK; ++r) {
        const v4f b = *(const v4f*)(B + r * D_FFN + f);
        const float m = mod[s * RANK + r];   // wave-uniform -> scalar load
        Bs[r] = b * m;
    }

    float* outp = out + ((size_t)(s * D_MODEL + d_base)) * D_FFN + f;

    #pragma unroll
    for (int dl = 0; dl < 16; ++dl) {
        const float* Ad = A + (size_t)(d_base + dl) * RANK;  // wave-uniform base
        v4f acc = {0.f, 0.f, 0.f, 0.f};
        #pragma unroll
        for (int r = 0; r < RANK; ++r) {
            const float a = Ad[r];            // wave-uniform -> s_load + SGPR-operand FMA
            acc += Bs[r] * a;
        }
        __builtin_nontemporal_store(acc, (v4f*)outp);
        outp += D_FFN;
    }
}

extern "C" void kernel_launch(void* const* d_in, const int* in_sizes, int n_in,
                              void* d_out, int out_size, void* d_ws, size_t ws_size,
                              hipStream_t stream) {
    const float* attn = (const float*)d_in[0];   // (1, 64, 768)
    const float* A    = (const float*)d_in[1];   // (768, 16)
    const float* B    = (const float*)d_in[2];   // (16, 3072)
    float*       out  = (float*)d_out;           // (1, 64, 768, 3072)
    float*       mod  = (float*)d_ws;            // 64*16 floats scratch

    hipLaunchKernelGGL(mod_kernel, dim3(SEQ), dim3(256), 0, stream, attn, A, mod);
    hipLaunchKernelGGL(delta_kernel,
                       dim3(D_FFN / 1024, D_MODEL / 16, SEQ), dim3(256), 0, stream,
                       A, B, mod, out);
}